// Round 1
// 161.701 us; speedup vs baseline: 1.0087x; 1.0087x over previous
//
#include <hip/hip_runtime.h>

// Bundle-adjustment reprojection residual.
// R8 post-mortem: resid_pipe 54.5us vs ~47us L1-request floor (27K req/CU
// x 4.2cyc). OccupancyPercent=44.5 is the tell: grid-stride gives 38% of
// threads a 3rd chunk and those threads are id-clustered (blocks 0..393),
// so the last ~1/3 of the kernel runs with most blocks retired -> MLP
// (and thus gather throughput) collapses in the tail. R9: balanced
// per-WAVE work ranges at wave-block (64-chunk) granularity:
//   wave w owns wave-blocks [w*NB/NW, (w+1)*NB/NW)
// -> 2-vs-3-iteration waves spread evenly over every CU (+-1 wave-block
// per CU), coalescing unchanged (64 lanes <-> 64 consecutive chunks),
// no atomics. Also: pack_poses folded into the resid preamble (fp32
// poses -> LDS fp16 directly), saving a dispatch. Layout unchanged:
// fp16 point table (8B rows, 4MB, L2-resident), fp16 poses in 32KB LDS,
// 4-obs gather batches, 1-deep index prefetch.

typedef float    vfloat4 __attribute__((ext_vector_type(4)));
typedef int      vint4   __attribute__((ext_vector_type(4)));
typedef _Float16 vhalf4  __attribute__((ext_vector_type(4)));
typedef _Float16 vhalf8  __attribute__((ext_vector_type(8)));

#define MAX_CAM 2000   // LDS fp16 pose table: 2000*16 = 32000 B

// ---- prep: points [N_PTS*3] f32 -> half4 rows (8 B) ----
__global__ __launch_bounds__(256) void pack_points_h(
    const float* __restrict__ src, vhalf4* __restrict__ dst, int n_pts)
{
    int i = blockIdx.x * blockDim.x + threadIdx.x;
    if (i >= n_pts) return;
    const float* s = src + 3 * i;
    vhalf4 v = {(_Float16)s[0], (_Float16)s[1], (_Float16)s[2], (_Float16)0.0f};
    dst[i] = v;
}

__device__ __forceinline__ void project1(
    vhalf4 P, vhalf8 Q, float fx, float fy, float cx, float cy,
    float* rx, float* ry)
{
    float px = (float)P.x, py = (float)P.y, pz = (float)P.z;
    float tx = (float)Q[0], ty = (float)Q[1], tz = (float)Q[2];
    float qx = (float)Q[3], qy = (float)Q[4],
          qz = (float)Q[5], qw = (float)Q[6];

    float ux = qy * pz - qz * py;
    float uy = qz * px - qx * pz;
    float uz = qx * py - qy * px;
    float wx = ux + qw * px;
    float wy = uy + qw * py;
    float wz = uz + qw * pz;
    float ccx = qy * wz - qz * wy;
    float ccy = qz * wx - qx * wz;
    float ccz = qx * wy - qy * wx;
    float X = px + 2.0f * ccx + tx;
    float Y = py + 2.0f * ccy + ty;
    float Z = pz + 2.0f * ccz + tz;

    float invz = 1.0f / Z;
    *rx = fx * X * invz + cx;
    *ry = fy * Y * invz + cy;
}

__global__ __launch_bounds__(512) void resid_bal(
    const float*  __restrict__ obs,      // [n*2]
    const float*  __restrict__ Kmat,     // [9]
    const float*  __restrict__ poses,    // [n_cam*7] f32 (raw)
    const vhalf4* __restrict__ points_h, // [n_pts]
    const int*    __restrict__ cidx,     // [n]
    const int*    __restrict__ pidx,     // [n]
    float*        __restrict__ out,      // [n*2]
    int n, int n_cam)
{
    __shared__ vhalf8 sposes[MAX_CAM];   // 32000 B

    // preamble: fp32 poses -> fp16 LDS rows (replaces pack_poses kernel)
    for (int r = threadIdx.x; r < n_cam; r += blockDim.x) {
        const float* s = poses + 7 * r;
        vhalf8 v = {(_Float16)s[0], (_Float16)s[1], (_Float16)s[2],
                    (_Float16)s[3], (_Float16)s[4], (_Float16)s[5],
                    (_Float16)s[6], (_Float16)0.0f};
        sposes[r] = v;
    }
    __syncthreads();

    float fx = Kmat[0], cx = Kmat[2];
    float fy = Kmat[4], cy = Kmat[5];

    int nchunk = n >> 2;                 // 4 obs per chunk
    int nwb    = nchunk >> 6;            // full wave-blocks (64 chunks each)
    int lane   = threadIdx.x & 63;
    int wave   = (blockIdx.x * blockDim.x + threadIdx.x) >> 6;
    int nwave  = (gridDim.x * blockDim.x) >> 6;

    // balanced contiguous wave-block range for this wave
    int wb  = (int)(((long long)wave       * nwb) / nwave);
    int wbe = (int)(((long long)(wave + 1) * nwb) / nwave);

    if (wb < wbe) {
        int i0 = (wb << 6) + lane;
        vint4 c_cur = __builtin_nontemporal_load((const vint4*)(cidx + 4 * i0));
        vint4 p_cur = __builtin_nontemporal_load((const vint4*)(pidx + 4 * i0));

        while (wb < wbe) {
            int i    = (wb << 6) + lane;
            int base = 4 * i;

            // ---- current chunk: 4 point gathers batched (L2-resident table) ----
            vhalf4 P0 = points_h[p_cur.x];
            vhalf4 P1 = points_h[p_cur.y];
            vhalf4 P2 = points_h[p_cur.z];
            vhalf4 P3 = points_h[p_cur.w];

            vfloat4 o01 = __builtin_nontemporal_load((const vfloat4*)(obs + 2 * base));
            vfloat4 o23 = __builtin_nontemporal_load((const vfloat4*)(obs + 2 * base + 4));

            // ---- prefetch next wave-block's indices (hides idx HBM latency) ----
            int wbn = wb + 1;
            vint4 c_nxt = c_cur, p_nxt = p_cur;
            if (wbn < wbe) {   // wave-uniform branch
                int inext = (wbn << 6) + lane;
                c_nxt = __builtin_nontemporal_load((const vint4*)(cidx + 4 * inext));
                p_nxt = __builtin_nontemporal_load((const vint4*)(pidx + 4 * inext));
            }

            // ---- pose lookups: one ds_read_b128 each (LDS pipe) ----
            vhalf8 Q0 = sposes[c_cur.x];
            vhalf8 Q1 = sposes[c_cur.y];
            vhalf8 Q2 = sposes[c_cur.z];
            vhalf8 Q3 = sposes[c_cur.w];

            vhalf4 P[4] = {P0, P1, P2, P3};
            vhalf8 Q[4] = {Q0, Q1, Q2, Q3};
            float res[8];
            #pragma unroll
            for (int k = 0; k < 4; ++k)
                project1(P[k], Q[k], fx, fy, cx, cy, &res[2 * k], &res[2 * k + 1]);

            vfloat4 r0 = {res[0] - o01.x, res[1] - o01.y, res[2] - o01.z, res[3] - o01.w};
            vfloat4 r1 = {res[4] - o23.x, res[5] - o23.y, res[6] - o23.z, res[7] - o23.w};
            __builtin_nontemporal_store(r0, (vfloat4*)(out + 2 * base));
            __builtin_nontemporal_store(r1, (vfloat4*)(out + 2 * base + 4));

            wb = wbn;
            c_cur = c_nxt;
            p_cur = p_nxt;
        }
    }

    // tail wave-block (nchunk % 64 chunks): wave 0 of block 0, guarded lanes
    if (blockIdx.x == 0 && threadIdx.x < 64) {
        int i = (nwb << 6) + lane;
        if (i < nchunk) {
            int base = 4 * i;
            vint4 c_cur = *(const vint4*)(cidx + 4 * i);
            vint4 p_cur = *(const vint4*)(pidx + 4 * i);
            vhalf4 P[4] = {points_h[p_cur.x], points_h[p_cur.y],
                           points_h[p_cur.z], points_h[p_cur.w]};
            vhalf8 Q[4] = {sposes[c_cur.x], sposes[c_cur.y],
                           sposes[c_cur.z], sposes[c_cur.w]};
            vfloat4 o01 = *(const vfloat4*)(obs + 2 * base);
            vfloat4 o23 = *(const vfloat4*)(obs + 2 * base + 4);
            float res[8];
            #pragma unroll
            for (int k = 0; k < 4; ++k)
                project1(P[k], Q[k], fx, fy, cx, cy, &res[2 * k], &res[2 * k + 1]);
            vfloat4 r0 = {res[0] - o01.x, res[1] - o01.y, res[2] - o01.z, res[3] - o01.w};
            vfloat4 r1 = {res[4] - o23.x, res[5] - o23.y, res[6] - o23.z, res[7] - o23.w};
            *(vfloat4*)(out + 2 * base)     = r0;
            *(vfloat4*)(out + 2 * base + 4) = r1;
        }
    }

    // remainder (n % 4): single thread, scalar path
    if (blockIdx.x == 0 && threadIdx.x == 0) {
        for (int j = (nchunk << 2); j < n; ++j) {
            vhalf4 P = points_h[pidx[j]];
            vhalf8 Q = sposes[cidx[j]];
            float rx, ry;
            project1(P, Q, fx, fy, cx, cy, &rx, &ry);
            out[2 * j]     = rx - obs[2 * j];
            out[2 * j + 1] = ry - obs[2 * j + 1];
        }
    }
}

// fallback (ws too small / too many cameras): scalar fp32 path
__global__ __launch_bounds__(256) void resid_fallback(
    const float* __restrict__ obs, const float* __restrict__ Kmat,
    const float* __restrict__ poses, const float* __restrict__ points,
    const int* __restrict__ cidx, const int* __restrict__ pidx,
    float* __restrict__ out, int n)
{
    int i = blockIdx.x * blockDim.x + threadIdx.x;
    if (i >= n) return;
    const float* ps = poses + 7 * cidx[i];
    const float* pt = points + 3 * pidx[i];
    float px = pt[0], py = pt[1], pz = pt[2];
    float tx = ps[0], ty = ps[1], tz = ps[2];
    float qx = ps[3], qy = ps[4], qz = ps[5], qw = ps[6];
    float ux = qy * pz - qz * py;
    float uy = qz * px - qx * pz;
    float uz = qx * py - qy * px;
    float wx = ux + qw * px;
    float wy = uy + qw * py;
    float wz = uz + qw * pz;
    float ccx = qy * wz - qz * wy;
    float ccy = qz * wx - qx * wz;
    float ccz = qx * wy - qy * wx;
    float X = px + 2.0f * ccx + tx;
    float Y = py + 2.0f * ccy + ty;
    float Z = pz + 2.0f * ccz + tz;
    float invz = 1.0f / Z;
    out[2 * i]     = Kmat[0] * X * invz + Kmat[2] - obs[2 * i];
    out[2 * i + 1] = Kmat[4] * Y * invz + Kmat[5] - obs[2 * i + 1];
}

extern "C" void kernel_launch(void* const* d_in, const int* in_sizes, int n_in,
                              void* d_out, int out_size, void* d_ws, size_t ws_size,
                              hipStream_t stream) {
    const float* obs    = (const float*)d_in[0];
    const float* Kmat   = (const float*)d_in[1];
    const float* poses  = (const float*)d_in[2];
    const float* points = (const float*)d_in[3];
    const int*   cidx   = (const int*)d_in[4];
    const int*   pidx   = (const int*)d_in[5];
    float*       out    = (float*)d_out;

    int n     = in_sizes[4];      // N_OBS
    int n_cam = in_sizes[2] / 7;  // 2000
    int n_pts = in_sizes[3] / 3;  // 500000

    size_t pts_bytes = (size_t)n_pts * sizeof(vhalf4);  // 4 MB

    if (ws_size < pts_bytes || n_cam > MAX_CAM) {
        resid_fallback<<<(n + 255) / 256, 256, 0, stream>>>(
            obs, Kmat, poses, points, cidx, pidx, out, n);
        return;
    }

    vhalf4* points_h = (vhalf4*)d_ws;

    pack_points_h<<<(n_pts + 255) / 256, 256, 0, stream>>>(points, points_h, n_pts);

    // 4 blocks/CU x 512 threads = 32 waves/CU (LDS 32KB/block caps at 4);
    // grid exactly fills the chip; balanced per-wave ranges kill the tail.
    int block = 512;
    int grid  = 1024;
    resid_bal<<<grid, block, 0, stream>>>(
        obs, Kmat, poses, points_h, cidx, pidx, out, n, n_cam);
}

// Round 4
// 161.293 us; speedup vs baseline: 1.0113x; 1.0025x over previous
//
#include <hip/hip_runtime.h>

// Bundle-adjustment reprojection residual.
// R11 note: bench infra failed ("container failed twice") -> no data; this
// is an unchanged resubmit. Distinguish from R10, where the Trio exception
// came from hipLaunchCooperativeKernel breaking graph capture (lesson kept:
// no cooperative launch in this harness).
// R11 = verified R8 resid loop (54.5us: grid-stride + 1-deep idx prefetch,
// packed fp16 pose table -> coalesced LDS fill) + two harness-safe salvages:
//   (a) pose packing merged INTO the pack dispatch (3 -> 2 dispatches;
//       R8->R9 showed one dispatch ~= 4us e2e),
//   (b) vectorized point pack (vfloat4 x3 -> vhalf8 x2 per 4 points).
// Layout: fp16 point table (8B rows, 4MB, L2-resident), fp16 poses
// (16B rows, 32KB) -> LDS, 4-obs gather batches, plain loads on the
// table gathers (nt would deprioritize its L2 residency).

typedef float    vfloat4 __attribute__((ext_vector_type(4)));
typedef int      vint4   __attribute__((ext_vector_type(4)));
typedef _Float16 vhalf4  __attribute__((ext_vector_type(4)));
typedef _Float16 vhalf8  __attribute__((ext_vector_type(8)));

#define MAX_CAM 2000   // LDS fp16 pose table: 2000*16 = 32000 B

// ---- prep: points f32[3] -> half4 rows (8B), poses f32[7] -> half8 rows (16B)
// One dispatch packs both tables: thread t handles 4 points; threads
// t < n_cam additionally pack one pose row.
__global__ __launch_bounds__(256) void pack_tables(
    const float* __restrict__ points, vhalf4* __restrict__ points_h, int n_pts,
    const float* __restrict__ poses,  vhalf8* __restrict__ poses_h,  int n_cam)
{
    int t = blockIdx.x * blockDim.x + threadIdx.x;

    // 4 points per thread: 48B read (3x vfloat4), 32B write (2x vhalf8)
    int npc = n_pts >> 2;
    if (t < npc) {
        const float* s = points + 12 * t;
        vfloat4 a = *(const vfloat4*)(s);
        vfloat4 b = *(const vfloat4*)(s + 4);
        vfloat4 d = *(const vfloat4*)(s + 8);
        vhalf8 h0 = {(_Float16)a.x, (_Float16)a.y, (_Float16)a.z, (_Float16)0.0f,
                     (_Float16)a.w, (_Float16)b.x, (_Float16)b.y, (_Float16)0.0f};
        vhalf8 h1 = {(_Float16)b.z, (_Float16)b.w, (_Float16)d.x, (_Float16)0.0f,
                     (_Float16)d.y, (_Float16)d.z, (_Float16)d.w, (_Float16)0.0f};
        *(vhalf8*)(points_h + 4 * t)     = h0;
        *(vhalf8*)(points_h + 4 * t + 2) = h1;
    }
    if (t == 0) {                       // n_pts % 4 tail (none at 500000)
        for (int p = npc << 2; p < n_pts; ++p) {
            const float* s = points + 3 * p;
            vhalf4 v = {(_Float16)s[0], (_Float16)s[1], (_Float16)s[2], (_Float16)0.0f};
            points_h[p] = v;
        }
    }
    if (t < n_cam) {                    // one pose row per thread
        const float* s = poses + 7 * t;
        vhalf8 v = {(_Float16)s[0], (_Float16)s[1], (_Float16)s[2],
                    (_Float16)s[3], (_Float16)s[4], (_Float16)s[5],
                    (_Float16)s[6], (_Float16)0.0f};
        poses_h[t] = v;
    }
}

__device__ __forceinline__ void project1(
    vhalf4 P, vhalf8 Q, float fx, float fy, float cx, float cy,
    float* rx, float* ry)
{
    float px = (float)P.x, py = (float)P.y, pz = (float)P.z;
    float tx = (float)Q[0], ty = (float)Q[1], tz = (float)Q[2];
    float qx = (float)Q[3], qy = (float)Q[4],
          qz = (float)Q[5], qw = (float)Q[6];

    float ux = qy * pz - qz * py;
    float uy = qz * px - qx * pz;
    float uz = qx * py - qy * px;
    float wx = ux + qw * px;
    float wy = uy + qw * py;
    float wz = uz + qw * pz;
    float ccx = qy * wz - qz * wy;
    float ccy = qz * wx - qx * wz;
    float ccz = qx * wy - qy * wx;
    float X = px + 2.0f * ccx + tx;
    float Y = py + 2.0f * ccy + ty;
    float Z = pz + 2.0f * ccz + tz;

    float invz = 1.0f / Z;
    *rx = fx * X * invz + cx;
    *ry = fy * Y * invz + cy;
}

// ---- R8's verified resid loop (54.5us): grid-stride + 1-deep idx prefetch
__global__ __launch_bounds__(512) void resid_pipe(
    const float*  __restrict__ obs,      // [n*2]
    const float*  __restrict__ Kmat,     // [9]
    const vhalf8* __restrict__ poses_h,  // [n_cam]
    const vhalf4* __restrict__ points_h, // [n_pts]
    const int*    __restrict__ cidx,     // [n]
    const int*    __restrict__ pidx,     // [n]
    float*        __restrict__ out,      // [n*2]
    int n, int n_cam)
{
    __shared__ vhalf8 sposes[MAX_CAM];   // 32000 B

    for (int r = threadIdx.x; r < n_cam; r += blockDim.x)
        sposes[r] = poses_h[r];
    __syncthreads();

    float fx = Kmat[0], cx = Kmat[2];
    float fy = Kmat[4], cy = Kmat[5];

    int nchunk = n >> 2;                       // 4 obs per chunk
    int tot    = gridDim.x * blockDim.x;
    int i      = blockIdx.x * blockDim.x + threadIdx.x;

    // prologue: indices for first chunk
    vint4 c_cur = {0, 0, 0, 0}, p_cur = {0, 0, 0, 0};
    if (i < nchunk) {
        c_cur = __builtin_nontemporal_load((const vint4*)(cidx + 4 * i));
        p_cur = __builtin_nontemporal_load((const vint4*)(pidx + 4 * i));
    }

    while (i < nchunk) {
        int base  = 4 * i;
        int inext = i + tot;

        // ---- current chunk: 4 point gathers batched (L2-resident table) ----
        vhalf4 P0 = points_h[p_cur.x];
        vhalf4 P1 = points_h[p_cur.y];
        vhalf4 P2 = points_h[p_cur.z];
        vhalf4 P3 = points_h[p_cur.w];

        vfloat4 o01 = __builtin_nontemporal_load((const vfloat4*)(obs + 2 * base));
        vfloat4 o23 = __builtin_nontemporal_load((const vfloat4*)(obs + 2 * base + 4));

        // ---- prefetch next chunk's indices (hides HBM latency of idx) ----
        vint4 c_nxt = c_cur, p_nxt = p_cur;
        if (inext < nchunk) {
            c_nxt = __builtin_nontemporal_load((const vint4*)(cidx + 4 * inext));
            p_nxt = __builtin_nontemporal_load((const vint4*)(pidx + 4 * inext));
        }

        // ---- pose lookups: one ds_read_b128 each (LDS pipe) ----
        vhalf8 Q0 = sposes[c_cur.x];
        vhalf8 Q1 = sposes[c_cur.y];
        vhalf8 Q2 = sposes[c_cur.z];
        vhalf8 Q3 = sposes[c_cur.w];

        vhalf4 P[4] = {P0, P1, P2, P3};
        vhalf8 Q[4] = {Q0, Q1, Q2, Q3};
        float res[8];
        #pragma unroll
        for (int k = 0; k < 4; ++k)
            project1(P[k], Q[k], fx, fy, cx, cy, &res[2 * k], &res[2 * k + 1]);

        vfloat4 r0 = {res[0] - o01.x, res[1] - o01.y, res[2] - o01.z, res[3] - o01.w};
        vfloat4 r1 = {res[4] - o23.x, res[5] - o23.y, res[6] - o23.z, res[7] - o23.w};
        __builtin_nontemporal_store(r0, (vfloat4*)(out + 2 * base));
        __builtin_nontemporal_store(r1, (vfloat4*)(out + 2 * base + 4));

        i = inext;
        c_cur = c_nxt;
        p_cur = p_nxt;
    }

    // remainder (n % 4): single thread, scalar path
    if (blockIdx.x == 0 && threadIdx.x == 0) {
        for (int j = (n >> 2) << 2; j < n; ++j) {
            vhalf4 P = points_h[pidx[j]];
            vhalf8 Q = sposes[cidx[j]];
            float rx, ry;
            project1(P, Q, fx, fy, cx, cy, &rx, &ry);
            out[2 * j]     = rx - obs[2 * j];
            out[2 * j + 1] = ry - obs[2 * j + 1];
        }
    }
}

// fallback (ws too small / too many cameras): scalar fp32 path
__global__ __launch_bounds__(256) void resid_fallback(
    const float* __restrict__ obs, const float* __restrict__ Kmat,
    const float* __restrict__ poses, const float* __restrict__ points,
    const int* __restrict__ cidx, const int* __restrict__ pidx,
    float* __restrict__ out, int n)
{
    int i = blockIdx.x * blockDim.x + threadIdx.x;
    if (i >= n) return;
    const float* ps = poses + 7 * cidx[i];
    const float* pt = points + 3 * pidx[i];
    float px = pt[0], py = pt[1], pz = pt[2];
    float tx = ps[0], ty = ps[1], tz = ps[2];
    float qx = ps[3], qy = ps[4], qz = ps[5], qw = ps[6];
    float ux = qy * pz - qz * py;
    float uy = qz * px - qx * pz;
    float uz = qx * py - qy * px;
    float wx = ux + qw * px;
    float wy = uy + qw * py;
    float wz = uz + qw * pz;
    float ccx = qy * wz - qz * wy;
    float ccy = qz * wx - qx * wz;
    float ccz = qx * wy - qy * wx;
    float X = px + 2.0f * ccx + tx;
    float Y = py + 2.0f * ccy + ty;
    float Z = pz + 2.0f * ccz + tz;
    float invz = 1.0f / Z;
    out[2 * i]     = Kmat[0] * X * invz + Kmat[2] - obs[2 * i];
    out[2 * i + 1] = Kmat[4] * Y * invz + Kmat[5] - obs[2 * i + 1];
}

extern "C" void kernel_launch(void* const* d_in, const int* in_sizes, int n_in,
                              void* d_out, int out_size, void* d_ws, size_t ws_size,
                              hipStream_t stream) {
    const float* obs    = (const float*)d_in[0];
    const float* Kmat   = (const float*)d_in[1];
    const float* poses  = (const float*)d_in[2];
    const float* points = (const float*)d_in[3];
    const int*   cidx   = (const int*)d_in[4];
    const int*   pidx   = (const int*)d_in[5];
    float*       out    = (float*)d_out;

    int n     = in_sizes[4];      // N_OBS
    int n_cam = in_sizes[2] / 7;  // 2000
    int n_pts = in_sizes[3] / 3;  // 500000

    size_t pts_bytes  = (size_t)n_pts * sizeof(vhalf4);  // 4 MB
    size_t pose_bytes = (size_t)n_cam * sizeof(vhalf8);  // 32 KB

    if (ws_size < pts_bytes + pose_bytes || n_cam > MAX_CAM) {
        resid_fallback<<<(n + 255) / 256, 256, 0, stream>>>(
            obs, Kmat, poses, points, cidx, pidx, out, n);
        return;
    }

    vhalf4* points_h = (vhalf4*)d_ws;
    vhalf8* poses_h  = (vhalf8*)((char*)d_ws + pts_bytes);

    // one pack dispatch covers 4-point chunks AND pose rows
    int pack_threads = (n_pts + 3) / 4;
    if (pack_threads < n_cam) pack_threads = n_cam;
    pack_tables<<<(pack_threads + 255) / 256, 256, 0, stream>>>(
        points, points_h, n_pts, poses, poses_h, n_cam);

    // 4 blocks/CU x 512 threads = 32 waves/CU; grid-stride loop
    // (~2.4 chunks/thread) so the prefetch pipeline has iterations to cover.
    int block = 512;
    int grid  = 1024;
    resid_pipe<<<grid, block, 0, stream>>>(
        obs, Kmat, poses_h, points_h, cidx, pidx, out, n, n_cam);
}